// Round 4
// baseline (270.383 us; speedup 1.0000x reference)
//
#include <hip/hip_runtime.h>
#include <cmath>

typedef __attribute__((ext_vector_type(8))) short bf16x8;
typedef __attribute__((ext_vector_type(4))) short s16x4;
typedef __attribute__((ext_vector_type(4))) float f32x4;

#define MFMA_BF16 __builtin_amdgcn_mfma_f32_16x16x32_bf16

__device__ __forceinline__ float bf2f(short s) {
    unsigned u = ((unsigned)(unsigned short)s) << 16;
    return __builtin_bit_cast(float, u);
}
__device__ __forceinline__ short f2bf(float f) {
    unsigned u = __builtin_bit_cast(unsigned, f);
    u += 0x7fffu + ((u >> 16) & 1u);   // RNE
    return (short)(u >> 16);
}

__device__ __forceinline__ void gl_lds16(const short* gp, short* lp) {
    __builtin_amdgcn_global_load_lds(
        (const __attribute__((address_space(1))) unsigned int*)gp,
        (__attribute__((address_space(3))) unsigned int*)lp, 16, 0, 0);
}

// 128x64-tile GEMM: C = A @ W^T (+bias). 4 waves 2x2 (wave = 64x32, 4x2
// accs), BK=64 double-buffered LDS (48 KB), one barrier per K-iter.
// Grid is 768 blocks = exactly 3 blocks/CU (grid-capped; R3 proved LDS
// reduction cannot raise occupancy), so keep the proven BK=64 barrier
// count.
// NEW (this round): fp32 operands are staged DIRECTLY from the original
// tensors via reg-staging (load fp32 -> cvt bf16 -> ds_write_b128), T14
// issue-early/write-late, which deletes the standalone cvt5 pass:
//   MODE 0: A = hidden_states fp32, W = Wq/Wk/Wv fp32 (per-block select).
//   MODE 1: A = abuf bf16 (global_load_lds), W = Wo fp32.
// Loop invariant: iter kt reads buf[kt&1], stages kt+1 into buf[kt&1 ^ 1];
// the single end-of-iter __syncthreads fences iter kt-1's readers of that
// buffer and drains gl_lds/ds_write (compiler emits vmcnt/lgkm before
// s_barrier).
// XCD region swizzle (T1): each XCD owns a gx/4 x gy/2 region (FETCH
// 39->28.8 MB measured in R3).
// LDS per 32-K half: 1KB chunks of 16 rows; XOR swizzle f(row)=(row>>1)&3:
// lane L holds (row = chunk*16 + L>>2, kq = (L&3)^f(L>>2)) at slot L;
// fragment read slot = l15*4 + (quad^f(l15)) -> conflict-free b128; the
// in-row 64B permutation keeps global loads coalesced.
// MODE 0: QKV fused epilogue; MODE 1: fp32 out + bias (bq slot).
template <int MODE>
__global__ __launch_bounds__(256) void gemm_t(
    const float* __restrict__ Af, const short* __restrict__ Abf,
    const float* __restrict__ Wqf, const float* __restrict__ Wkf,
    const float* __restrict__ Wvf,
    const float* __restrict__ bq, const float* __restrict__ bk,
    const float* __restrict__ bv,
    short* __restrict__ qo, short* __restrict__ ko, short* __restrict__ vo,
    float* __restrict__ fo,
    int M, int K, int S, int Hkv, int Nq, int Nkv, int N)
{
    __shared__ __align__(16) short As[2][2 * 8 * 512];   // 2 bufs x 16KB
    __shared__ __align__(16) short Bs[2][2 * 4 * 512];   // 2 bufs x 8KB

    const int w    = threadIdx.x >> 6;
    const int lane = threadIdx.x & 63;
    const int l15  = lane & 15;
    const int quad = lane >> 4;
    const int wy   = w >> 1;
    const int wx   = w & 1;

    // XCD region swizzle (bijective): xcd = lin&7 owns a gx/4 x gy/2 patch.
    unsigned gx = gridDim.x, gy = gridDim.y;
    unsigned bx = blockIdx.x, by = blockIdx.y;
    if ((gx & 3) == 0 && (gy & 1) == 0) {
        unsigned lin = by * gx + bx;
        unsigned xcd = lin & 7, idx = lin >> 3;
        unsigned n   = gx >> 2;
        bx = (xcd & 3) * n + idx % n;
        by = (xcd >> 2) * (gy >> 1) + idx / n;
    }
    const int m0 = by * 128;
    const int n0 = bx * 64;

    // W base pointer (fp32, K-stride rows).
    const float* Wb;
    if (MODE == 1 || n0 < Nq)  Wb = Wqf + (size_t)n0 * K;
    else if (n0 < Nq + Nkv)    Wb = Wkf + (size_t)(n0 - Nq) * K;
    else                       Wb = Wvf + (size_t)(n0 - Nq - Nkv) * K;

    const float* Abase_f = (MODE == 0) ? Af  + (size_t)m0 * K : nullptr;
    const short* Abase_h = (MODE == 1) ? Abf + (size_t)m0 * K : nullptr;

    const int srow = lane >> 2;                              // 0..15
    const int scol = ((lane & 3) ^ ((srow >> 1) & 3)) * 8;   // swizzled col

    float4 ra[2][2][2];   // [h2][chunk-i][half]  (MODE 0 only)
    float4 rb[2][2];      // [h2][half]

    auto loadW = [&](int kofs) {
#pragma unroll
        for (int h2 = 0; h2 < 2; h2++) {
            const float* p = Wb + (size_t)(w * 16 + srow) * K + kofs + h2 * 32 + scol;
            rb[h2][0] = *(const float4*)p;
            rb[h2][1] = *(const float4*)(p + 4);
        }
    };
    auto loadA = [&](int kofs) {
#pragma unroll
        for (int h2 = 0; h2 < 2; h2++)
#pragma unroll
            for (int i = 0; i < 2; i++) {
                const int c = 2 * w + i;
                const float* p = Abase_f + (size_t)(c * 16 + srow) * K + kofs + h2 * 32 + scol;
                ra[h2][i][0] = *(const float4*)p;
                ra[h2][i][1] = *(const float4*)(p + 4);
            }
    };
    auto stageA_lds = [&](int buf, int kofs) {
#pragma unroll
        for (int h2 = 0; h2 < 2; h2++)
#pragma unroll
            for (int i = 0; i < 2; i++) {
                const int c = 2 * w + i;
                gl_lds16(Abase_h + (size_t)(c * 16 + srow) * K + kofs + h2 * 32 + scol,
                         As[buf] + h2 * 4096 + c * 512 + lane * 8);
            }
    };
    auto cvt8 = [&](float4 lo, float4 hi) {
        bf16x8 v;
        v[0] = f2bf(lo.x); v[1] = f2bf(lo.y); v[2] = f2bf(lo.z); v[3] = f2bf(lo.w);
        v[4] = f2bf(hi.x); v[5] = f2bf(hi.y); v[6] = f2bf(hi.z); v[7] = f2bf(hi.w);
        return v;
    };
    auto writeW = [&](int buf) {
#pragma unroll
        for (int h2 = 0; h2 < 2; h2++)
            *(bf16x8*)(Bs[buf] + h2 * 2048 + w * 512 + lane * 8) = cvt8(rb[h2][0], rb[h2][1]);
    };
    auto writeA = [&](int buf) {
#pragma unroll
        for (int h2 = 0; h2 < 2; h2++)
#pragma unroll
            for (int i = 0; i < 2; i++) {
                const int c = 2 * w + i;
                *(bf16x8*)(As[buf] + h2 * 4096 + c * 512 + lane * 8) =
                    cvt8(ra[h2][i][0], ra[h2][i][1]);
            }
    };

    f32x4 acc[4][2];
#pragma unroll
    for (int i = 0; i < 4; i++)
#pragma unroll
        for (int j = 0; j < 2; j++) acc[i][j] = f32x4{0.f, 0.f, 0.f, 0.f};

    const int ridx = (l15 * 4 + (quad ^ ((l15 >> 1) & 3))) * 8;
    const int nk = K / 64;

    // prologue: stage tile 0 into buf 0
    if constexpr (MODE == 0) { loadA(0); } else { stageA_lds(0, 0); }
    loadW(0);
    if constexpr (MODE == 0) writeA(0);
    writeW(0);
    __syncthreads();

    for (int kt = 0; kt < nk; kt++) {
        const int cur = kt & 1;
        const int nxt = cur ^ 1;
        const bool pf = (kt + 1 < nk);
        if (pf) {   // issue next-tile global loads early (T14)
            if constexpr (MODE == 0) loadA((kt + 1) * 64);
            else                     stageA_lds(nxt, (kt + 1) * 64);
            loadW((kt + 1) * 64);
        }

#pragma unroll
        for (int h2 = 0; h2 < 2; h2++) {
            bf16x8 af[4], bfr[2];
#pragma unroll
            for (int i = 0; i < 4; i++)
                af[i] = *(const bf16x8*)(As[cur] + h2 * 4096 + (wy * 4 + i) * 512 + ridx);
#pragma unroll
            for (int j = 0; j < 2; j++)
                bfr[j] = *(const bf16x8*)(Bs[cur] + h2 * 2048 + (wx * 2 + j) * 512 + ridx);
#pragma unroll
            for (int i = 0; i < 4; i++)
#pragma unroll
                for (int j = 0; j < 2; j++)
                    acc[i][j] = MFMA_BF16(af[i], bfr[j], acc[i][j], 0, 0, 0);
        }

        if (pf) {   // convert + LDS write late, under the MFMA shadow
            if constexpr (MODE == 0) writeA(nxt);
            writeW(nxt);
        }
        __syncthreads();
    }

#pragma unroll
    for (int i = 0; i < 4; i++) {
#pragma unroll
        for (int j = 0; j < 2; j++) {
            const int col = n0 + wx * 32 + j * 16 + l15;
#pragma unroll
            for (int r = 0; r < 4; r++) {
                const int row = m0 + wy * 64 + i * 16 + quad * 4 + r;
                float v = acc[i][j][r];
                if constexpr (MODE == 0) {
                    if (col < Nq) {
                        qo[(size_t)row * Nq + col] = f2bf(v + bq[col]);
                    } else if (col < Nq + Nkv) {
                        int cn = col - Nq;
                        ko[(size_t)row * Nkv + cn] = f2bf(v + bk[cn]);
                    } else {
                        int cn = col - Nq - Nkv;
                        int b  = row / S, s = row - b * S;
                        int hk = cn >> 7, dh = cn & 127;   // Dh == 128
                        vo[(size_t)((b * Hkv + hk) * 128 + dh) * S + s] = f2bf(v + bv[cn]);
                    }
                } else {
                    fo[(size_t)row * N + col] = v + bq[col];
                }
            }
        }
    }
}

// Fused per-(token, head) LayerNorm (Dh=128) + RoPE for Q and K in one
// launch. Blocks [0, nq/4) handle Q rows, the rest K rows.
__global__ __launch_bounds__(256) void ln_rope2(
    const short* __restrict__ Xq, short* __restrict__ Yq,
    const short* __restrict__ Xk, short* __restrict__ Yk,
    const float* __restrict__ qg, const float* __restrict__ qbe,
    const float* __restrict__ kg, const float* __restrict__ kbe,
    const float* __restrict__ cosp, const float* __restrict__ sinp,
    int H, int Hkv, int S, int nq)
{
    int gw = blockIdx.x * 4 + (threadIdx.x >> 6);
    const int lane = threadIdx.x & 63;
    const short* X; short* Y; const float* g; const float* bt; int Hc;
    if (gw < nq) { X = Xq; Y = Yq; g = qg; bt = qbe; Hc = H; }
    else { gw -= nq; X = Xk; Y = Yk; g = kg; bt = kbe; Hc = Hkv; }

    const int h  = gw % Hc;
    const int rs = gw / Hc;          // b*S + s
    const int b  = rs / S;
    const int s  = rs - b * S;

    const short* x = X + ((size_t)rs * Hc + h) * 128;
    float x0 = bf2f(x[lane]), x1 = bf2f(x[lane + 64]);

    float sum = x0 + x1;
    float sq  = x0 * x0 + x1 * x1;
#pragma unroll
    for (int off = 32; off > 0; off >>= 1) {
        sum += __shfl_xor(sum, off, 64);
        sq  += __shfl_xor(sq, off, 64);
    }
    float mu  = sum * (1.f / 128.f);
    float var = sq * (1.f / 128.f) - mu * mu;
    float rinv = rsqrtf(var + 1e-5f);

    float y0 = (x0 - mu) * rinv * g[lane]      + bt[lane];
    float y1 = (x1 - mu) * rinv * g[lane + 64] + bt[lane + 64];

    float c0 = cosp[(size_t)s * 128 + lane];
    float c1 = cosp[(size_t)s * 128 + lane + 64];
    float s0 = sinp[(size_t)s * 128 + lane];
    float s1 = sinp[(size_t)s * 128 + lane + 64];

    float o0 = y0 * c0 - y1 * s0;
    float o1 = y1 * c1 + y0 * s1;

    short* yp = Y + ((size_t)(b * Hc + h) * S + s) * 128;
    yp[lane]      = f2bf(o0);
    yp[lane + 64] = f2bf(o1);
}

// Flash attention v3 (proven ~39us): transposed-score formulation +
// block-shared LDS staging, double-buffered.
// Q: bf16 (B,H,S,128). Kt: (B,Hkv,S,128). Vt: (B,Hkv,128,S). O: (B,S,H*128).
__global__ __launch_bounds__(256, 2) void attn(
    const short* __restrict__ Q, const short* __restrict__ Kt,
    const short* __restrict__ Vt, short* __restrict__ O,
    int S, int H, int Hkv, int nrep, float scale)
{
    __shared__ __align__(16) short Ks[2][16 * 512];
    __shared__ __align__(16) short Vs[2][16 * 512];
    __shared__ __align__(16) short P[4][16][72];

    const int w    = threadIdx.x >> 6;
    const int lane = threadIdx.x & 63;
    const int l15  = lane & 15;
    const int quad = lane >> 4;
    const int bh   = blockIdx.x;
    const int h    = bh % H;
    const int b    = bh / H;
    const int nyt  = gridDim.y;
    const int y    = blockIdx.y;
    const int qblk = (y < (nyt >> 1)) ? (nyt - 1 - y) : (y - (nyt >> 1));
    const int hk   = h / nrep;
    const int m0   = qblk * 64 + w * 16;
    const int qpos = m0 + l15;

    const short* qb = Q  + (size_t)(b * H + h) * S * 128;
    const short* kb = Kt + (size_t)(b * Hkv + hk) * S * 128;
    const short* vb = Vt + (size_t)(b * Hkv + hk) * 128 * S;

    auto stage = [&](int buf, int j0) {
#pragma unroll
        for (int i = 0; i < 8; i++) {
            if (w < 2) {
                const int s = w * 8 + i;
                const int t = s >> 2, c = s & 3;
                gl_lds16(kb + (size_t)(j0 + t * 16 + l15) * 128 + c * 32 + quad * 8,
                         Ks[buf] + s * 512 + lane * 8);
            } else {
                const int u = (w - 2) * 8 + i;
                const int c = u >> 1, hf = u & 1;
                gl_lds16(vb + (size_t)(c * 16 + l15) * S + j0 + hf * 32 + quad * 8,
                         Vs[buf] + u * 512 + lane * 8);
            }
        }
    };

    bf16x8 qf[4];
#pragma unroll
    for (int c = 0; c < 4; c++)
        qf[c] = *(const bf16x8*)(qb + (size_t)(m0 + l15) * 128 + c * 32 + quad * 8);

    f32x4 of[8];
#pragma unroll
    for (int c = 0; c < 8; c++) of[c] = f32x4{0.f, 0.f, 0.f, 0.f};
    float m_s = -1e30f, l_s = 0.f;
    const float c2 = scale * 1.44269504f;

    const int nkt = qblk + 1;
    stage(0, 0);
    __syncthreads();

    for (int kt = 0; kt < nkt; kt++) {
        const int cur = kt & 1;
        if (kt + 1 < nkt) stage(cur ^ 1, (kt + 1) * 64);

        const short* Kb = Ks[cur];
        const short* Vb = Vs[cur];
        const int j0 = kt * 64;

        f32x4 sc[4];
#pragma unroll
        for (int t = 0; t < 4; t++) sc[t] = f32x4{0.f, 0.f, 0.f, 0.f};
#pragma unroll
        for (int c = 0; c < 4; c++)
#pragma unroll
            for (int t = 0; t < 4; t++) {
                bf16x8 kf = *(const bf16x8*)(Kb + (t * 4 + c) * 512 + lane * 8);
                sc[t] = MFMA_BF16(kf, qf[c], sc[t], 0, 0, 0);
            }

        float v[4][4];
        float mx = -1e30f;
#pragma unroll
        for (int t = 0; t < 4; t++)
#pragma unroll
            for (int r = 0; r < 4; r++) {
                float s_ = sc[t][r];
                if (j0 + t * 16 + quad * 4 + r > qpos) s_ = -1e30f;
                v[t][r] = s_;
                mx = fmaxf(mx, s_);
            }
        mx = fmaxf(mx, __shfl_xor(mx, 16, 64));
        mx = fmaxf(mx, __shfl_xor(mx, 32, 64));
        float mnew  = fmaxf(m_s, mx);
        float mc    = mnew * c2;
        float alpha = exp2f(m_s * c2 - mc);
        float sum = 0.f;
        float p[4][4];
#pragma unroll
        for (int t = 0; t < 4; t++)
#pragma unroll
            for (int r = 0; r < 4; r++) {
                p[t][r] = exp2f(__builtin_fmaf(v[t][r], c2, -mc));
                sum += p[t][r];
            }
        sum += __shfl_xor(sum, 16, 64);
        sum += __shfl_xor(sum, 32, 64);
        l_s = l_s * alpha + sum;
        m_s = mnew;

#pragma unroll
        for (int c = 0; c < 8; c++) {
            f32x4 t = of[c];
            t[0] *= alpha; t[1] *= alpha; t[2] *= alpha; t[3] *= alpha;
            of[c] = t;
        }

#pragma unroll
        for (int t = 0; t < 4; t++) {
            s16x4 pk;
#pragma unroll
            for (int r = 0; r < 4; r++) pk[r] = f2bf(p[t][r]);
            *(s16x4*)(&P[w][l15][t * 16 + quad * 4]) = pk;
        }
        bf16x8 pb0 = *(const bf16x8*)(&P[w][l15][quad * 8]);
        bf16x8 pb1 = *(const bf16x8*)(&P[w][l15][32 + quad * 8]);

#pragma unroll
        for (int c = 0; c < 8; c++) {
            bf16x8 vf0 = *(const bf16x8*)(Vb + (c * 2 + 0) * 512 + lane * 8);
            bf16x8 vf1 = *(const bf16x8*)(Vb + (c * 2 + 1) * 512 + lane * 8);
            of[c] = MFMA_BF16(vf0, pb0, of[c], 0, 0, 0);
            of[c] = MFMA_BF16(vf1, pb1, of[c], 0, 0, 0);
        }
        __syncthreads();
    }

    const int HDh = H * 128;
    const float rinv = 1.0f / l_s;
    short* orow = O + ((size_t)b * S + qpos) * HDh + h * 128;
#pragma unroll
    for (int c = 0; c < 8; c++) {
        s16x4 ov;
#pragma unroll
        for (int r = 0; r < 4; r++) ov[r] = f2bf(of[c][r] * rinv);
        *(s16x4*)(orow + c * 16 + quad * 4) = ov;
    }
}

extern "C" void kernel_launch(void* const* d_in, const int* in_sizes, int n_in,
                              void* d_out, int out_size, void* d_ws, size_t ws_size,
                              hipStream_t stream) {
    const float* hs   = (const float*)d_in[0];
    const float* cosp = (const float*)d_in[1];
    const float* sinp = (const float*)d_in[2];
    const float* Wq   = (const float*)d_in[3];
    const float* bq   = (const float*)d_in[4];
    const float* Wk   = (const float*)d_in[5];
    const float* bk   = (const float*)d_in[6];
    const float* Wv   = (const float*)d_in[7];
    const float* bv   = (const float*)d_in[8];
    const float* Wo   = (const float*)d_in[9];
    const float* bo   = (const float*)d_in[10];
    const float* qg   = (const float*)d_in[11];
    const float* qb_  = (const float*)d_in[12];
    const float* kg   = (const float*)d_in[13];
    const float* kb_  = (const float*)d_in[14];

    const int Dh    = in_sizes[11];          // 128
    const int Dm    = in_sizes[10];          // 2048
    const int HDh   = in_sizes[4];           // 2048
    const int H     = HDh / Dh;              // 16
    const int HkvDh = in_sizes[6];           // 512
    const int Hkv   = HkvDh / Dh;            // 4
    const int S     = in_sizes[1] / Dh;      // 1024
    const int B     = in_sizes[0] / (S * Dm);// 2
    const int M     = B * S;                 // 2048
    const int nrep  = H / Hkv;               // 4

    // workspace layout (cvt buffers gone: gemms read fp32 directly)
    char* ws = (char*)d_ws;
    short* qg16 = (short*)ws;  ws += (size_t)M * HDh     * 2;  // 8 MB
    short* kg16 = (short*)ws;  ws += (size_t)M * HkvDh   * 2;  // 2 MB
    short* qbuf = (short*)ws;  ws += (size_t)M * HDh     * 2;  // 8 MB
    short* kbuf = (short*)ws;  ws += (size_t)M * HkvDh   * 2;  // 2 MB
    short* vbuf = (short*)ws;  ws += (size_t)M * HkvDh   * 2;  // 2 MB
    short* abuf = qg16;   // alias: q-gemm output dead after ln_rope

    dim3 blk(256);
    const int Ntot = HDh + 2 * HkvDh;  // 3072
    gemm_t<0><<<dim3(Ntot / 64, M / 128), blk, 0, stream>>>(
        hs, nullptr, Wq, Wk, Wv, bq, bk, bv,
        qg16, kg16, vbuf, nullptr,
        M, Dm, S, Hkv, HDh, HkvDh, Ntot);

    const int nq = M * H;   // 32768 q row-heads
    ln_rope2<<<dim3((nq + M * Hkv) / 4), blk, 0, stream>>>(
        qg16, qbuf, kg16, kbuf, qg, qb_, kg, kb_, cosp, sinp, H, Hkv, S, nq);

    const float scale = 1.0f / sqrtf((float)Dh);
    attn<<<dim3(H * B, S / 64), blk, 0, stream>>>(qbuf, kbuf, vbuf, abuf, S, H, Hkv, nrep, scale);

    gemm_t<1><<<dim3(Dm / 64, M / 128), blk, 0, stream>>>(
        nullptr, abuf, Wo, nullptr, nullptr, bo, nullptr, nullptr,
        nullptr, nullptr, nullptr, (float*)d_out,
        M, HDh, S, Hkv, Dm, 0, Dm);
}

// Round 5
// 241.220 us; speedup vs baseline: 1.1209x; 1.1209x over previous
//
#include <hip/hip_runtime.h>
#include <cmath>

typedef __attribute__((ext_vector_type(8))) short bf16x8;
typedef __attribute__((ext_vector_type(4))) short s16x4;
typedef __attribute__((ext_vector_type(4))) float f32x4;

#define MFMA_BF16 __builtin_amdgcn_mfma_f32_16x16x32_bf16

__device__ __forceinline__ float bf2f(short s) {
    unsigned u = ((unsigned)(unsigned short)s) << 16;
    return __builtin_bit_cast(float, u);
}
__device__ __forceinline__ short f2bf(float f) {
    unsigned u = __builtin_bit_cast(unsigned, f);
    u += 0x7fffu + ((u >> 16) & 1u);   // RNE
    return (short)(u >> 16);
}

__device__ __forceinline__ void gl_lds16(const short* gp, short* lp) {
    __builtin_amdgcn_global_load_lds(
        (const __attribute__((address_space(1))) unsigned int*)gp,
        (__attribute__((address_space(3))) unsigned int*)lp, 16, 0, 0);
}

// Fused fp32->bf16 conversion for 5 tensors; every segment size is a
// multiple of 1024 so each 256-thread block (4 elems/thread) stays in one.
// (R4 proved this dedup pass is essential: fusing cvt into the GEMMs
// tripled FETCH_SIZE, 29->84 MB, and cost +30us.)
__global__ __launch_bounds__(256) void cvt5(
    const float* s0, short* d0, int n0,
    const float* s1, short* d1, int n1,
    const float* s2, short* d2, int n2,
    const float* s3, short* d3, int n3,
    const float* s4, short* d4, int n4)
{
    long long i = (long long)blockIdx.x * 1024 + threadIdx.x * 4;
    const float* s; short* d;
    if      (i < n0)                  { s = s0; d = d0; }
    else if ((i -= n0) < n1)          { s = s1; d = d1; }
    else if ((i -= n1) < n2)          { s = s2; d = d2; }
    else if ((i -= n2) < n3)          { s = s3; d = d3; }
    else      { i -= n3;                s = s4; d = d4; }
    float4 v = *(const float4*)(s + i);
    s16x4 o;
    o[0] = f2bf(v.x); o[1] = f2bf(v.y); o[2] = f2bf(v.z); o[3] = f2bf(v.w);
    *(s16x4*)(d + i) = o;
}

// 128x64-tile GEMM (proven 55.6us config): C = A @ W^T (+bias). 4 waves
// 2x2 (wave = 64x32, 4x2 accs), BK=64 double-buffered LDS (48 KB),
// global_load_lds staging, one __syncthreads per K-iter.
// XCD region swizzle (T1): each XCD owns a gx/4 x gy/2 region
// (FETCH 39->28.8 MB measured in R3; time-neutral).
// LDS: per 32-K half, 1KB chunks of 16 rows; XOR swizzle f(row)=(row>>1)&3:
// lane L stages (row = chunk*16 + L>>2, kq = (L&3)^f(L>>2)) at slot L;
// fragment read slot = l15*4 + (quad^f(l15)) -> slot%8 distinct per octet
// (conflict-free b128), and the in-row 64B permutation keeps coalescing.
// MODE 0: QKV fused epilogue.
template <int MODE>
__global__ __launch_bounds__(256) void gemm_t(
    const short* __restrict__ A, const short* __restrict__ W,
    const float* __restrict__ bq, const float* __restrict__ bk,
    const float* __restrict__ bv,
    short* __restrict__ qo, short* __restrict__ ko, short* __restrict__ vo,
    float* __restrict__ fo,
    int M, int K, int S, int Hkv, int Nq, int Nkv, int N)
{
    __shared__ __align__(16) short As[2][2 * 8 * 512];   // 2 halves x 8 chunks
    __shared__ __align__(16) short Bs[2][2 * 4 * 512];   // 2 halves x 4 chunks

    const int w    = threadIdx.x >> 6;
    const int lane = threadIdx.x & 63;
    const int l15  = lane & 15;
    const int quad = lane >> 4;
    const int wy   = w >> 1;
    const int wx   = w & 1;

    // XCD region swizzle (bijective): xcd = lin&7 owns a gx/4 x gy/2 patch.
    unsigned gx = gridDim.x, gy = gridDim.y;
    unsigned bx = blockIdx.x, by = blockIdx.y;
    if ((gx & 3) == 0 && (gy & 1) == 0) {
        unsigned lin = by * gx + bx;
        unsigned xcd = lin & 7, idx = lin >> 3;
        unsigned n   = gx >> 2;
        bx = (xcd & 3) * n + idx % n;
        by = (xcd >> 2) * (gy >> 1) + idx / n;
    }
    const int m0 = by * 128;
    const int n0 = bx * 64;

    const short* Ab = A + (size_t)m0 * K;
    const short* Wb = W + (size_t)n0 * K;

    const int srow = lane >> 2;                              // 0..15
    const int scol = ((lane & 3) ^ ((srow >> 1) & 3)) * 8;   // swizzled col
    auto stage = [&](int buf, int kofs) {
#pragma unroll
        for (int h2 = 0; h2 < 2; h2++) {
#pragma unroll
            for (int i = 0; i < 2; i++) {
                const int c = 2 * w + i;
                gl_lds16(Ab + (size_t)(c * 16 + srow) * K + kofs + h2 * 32 + scol,
                         As[buf] + h2 * 4096 + c * 512 + lane * 8);
            }
            gl_lds16(Wb + (size_t)(w * 16 + srow) * K + kofs + h2 * 32 + scol,
                     Bs[buf] + h2 * 2048 + w * 512 + lane * 8);
        }
    };

    f32x4 acc[4][2];
#pragma unroll
    for (int i = 0; i < 4; i++)
#pragma unroll
        for (int j = 0; j < 2; j++) acc[i][j] = f32x4{0.f, 0.f, 0.f, 0.f};

    const int ridx = (l15 * 4 + (quad ^ ((l15 >> 1) & 3))) * 8;
    const int nk = K / 64;
    stage(0, 0);
    __syncthreads();

    for (int kt = 0; kt < nk; kt++) {
        const int cur = kt & 1;
        if (kt + 1 < nk) stage(cur ^ 1, (kt + 1) * 64);

#pragma unroll
        for (int h2 = 0; h2 < 2; h2++) {
            bf16x8 af[4], bfr[2];
#pragma unroll
            for (int i = 0; i < 4; i++)
                af[i] = *(const bf16x8*)(As[cur] + h2 * 4096 + (wy * 4 + i) * 512 + ridx);
#pragma unroll
            for (int j = 0; j < 2; j++)
                bfr[j] = *(const bf16x8*)(Bs[cur] + h2 * 2048 + (wx * 2 + j) * 512 + ridx);
#pragma unroll
            for (int i = 0; i < 4; i++)
#pragma unroll
                for (int j = 0; j < 2; j++)
                    acc[i][j] = MFMA_BF16(af[i], bfr[j], acc[i][j], 0, 0, 0);
        }
        __syncthreads();
    }

#pragma unroll
    for (int i = 0; i < 4; i++) {
#pragma unroll
        for (int j = 0; j < 2; j++) {
            const int col = n0 + wx * 32 + j * 16 + l15;
#pragma unroll
            for (int r = 0; r < 4; r++) {
                const int row = m0 + wy * 64 + i * 16 + quad * 4 + r;
                float v = acc[i][j][r];
                if (col < Nq) {
                    qo[(size_t)row * Nq + col] = f2bf(v + bq[col]);
                } else if (col < Nq + Nkv) {
                    int cn = col - Nq;
                    ko[(size_t)row * Nkv + cn] = f2bf(v + bk[cn]);
                } else {
                    int cn = col - Nq - Nkv;
                    int b  = row / S, s = row - b * S;
                    int hk = cn >> 7, dh = cn & 127;   // Dh == 128
                    vo[(size_t)((b * Hkv + hk) * 128 + dh) * S + s] = f2bf(v + bv[cn]);
                }
            }
        }
    }
}

// 64x64-tile GEMM for the output projection: out = A @ W^T + bias (fp32).
// gemm1 was the most grid-starved dispatch: 128x64 tiles -> 512 blocks =
// 2 blocks/CU = 8 waves/CU. 64x64 tiles -> 1024 blocks, 32KB LDS -> 4
// blocks/CU = 16 waves/CU: double the independent-block pool per CU so
// barrier drains overlap (unlike R3, barriers-per-block is unchanged).
// 4 waves 2x2, wave = 32x32 (2x2 f32x4 accs), BK=64 double-buffered.
// Same 1KB-chunk swizzled LDS layout; wave w stages chunk w of each
// (operand, K-half) pair -> 4 gl_lds16/thread/buffer.
__global__ __launch_bounds__(256) void gemm64(
    const short* __restrict__ A, const short* __restrict__ W,
    const float* __restrict__ bias, float* __restrict__ out,
    int K, int N)
{
    __shared__ __align__(16) short As[2][2 * 4 * 512];   // 2 bufs x 8KB
    __shared__ __align__(16) short Bs[2][2 * 4 * 512];   // 2 bufs x 8KB

    const int w    = threadIdx.x >> 6;
    const int lane = threadIdx.x & 63;
    const int l15  = lane & 15;
    const int quad = lane >> 4;
    const int wy   = w >> 1;
    const int wx   = w & 1;

    unsigned gx = gridDim.x, gy = gridDim.y;
    unsigned bx = blockIdx.x, by = blockIdx.y;
    if ((gx & 3) == 0 && (gy & 1) == 0) {
        unsigned lin = by * gx + bx;
        unsigned xcd = lin & 7, idx = lin >> 3;
        unsigned n   = gx >> 2;
        bx = (xcd & 3) * n + idx % n;
        by = (xcd >> 2) * (gy >> 1) + idx / n;
    }
    const int m0 = by * 64;
    const int n0 = bx * 64;

    const short* Ab = A + (size_t)m0 * K;
    const short* Wb = W + (size_t)n0 * K;

    const int srow = lane >> 2;                              // 0..15
    const int scol = ((lane & 3) ^ ((srow >> 1) & 3)) * 8;   // swizzled col
    auto stage = [&](int buf, int kofs) {
#pragma unroll
        for (int h2 = 0; h2 < 2; h2++) {
            gl_lds16(Ab + (size_t)(w * 16 + srow) * K + kofs + h2 * 32 + scol,
                     As[buf] + h2 * 2048 + w * 512 + lane * 8);
            gl_lds16(Wb + (size_t)(w * 16 + srow) * K + kofs + h2 * 32 + scol,
                     Bs[buf] + h2 * 2048 + w * 512 + lane * 8);
        }
    };

    f32x4 acc[2][2];
#pragma unroll
    for (int i = 0; i < 2; i++)
#pragma unroll
        for (int j = 0; j < 2; j++) acc[i][j] = f32x4{0.f, 0.f, 0.f, 0.f};

    const int ridx = (l15 * 4 + (quad ^ ((l15 >> 1) & 3))) * 8;
    const int nk = K / 64;
    stage(0, 0);
    __syncthreads();

    for (int kt = 0; kt < nk; kt++) {
        const int cur = kt & 1;
        if (kt + 1 < nk) stage(cur ^ 1, (kt + 1) * 64);

#pragma unroll
        for (int h2 = 0; h2 < 2; h2++) {
            bf16x8 af[2], bfr[2];
#pragma unroll
            for (int i = 0; i < 2; i++)
                af[i] = *(const bf16x8*)(As[cur] + h2 * 2048 + (wy * 2 + i) * 512 + ridx);
#pragma unroll
            for (int j = 0; j < 2; j++)
                bfr[j] = *(const bf16x8*)(Bs[cur] + h2 * 2048 + (wx * 2 + j) * 512 + ridx);
#pragma unroll
            for (int i = 0; i < 2; i++)
#pragma unroll
                for (int j = 0; j < 2; j++)
                    acc[i][j] = MFMA_BF16(af[i], bfr[j], acc[i][j], 0, 0, 0);
        }
        __syncthreads();
    }

#pragma unroll
    for (int i = 0; i < 2; i++) {
#pragma unroll
        for (int j = 0; j < 2; j++) {
            const int col = n0 + wx * 32 + j * 16 + l15;
#pragma unroll
            for (int r = 0; r < 4; r++) {
                const int row = m0 + wy * 32 + i * 16 + quad * 4 + r;
                out[(size_t)row * N + col] = acc[i][j][r] + bias[col];
            }
        }
    }
}

// Fused per-(token, head) LayerNorm (Dh=128) + RoPE for Q and K in one
// launch. Blocks [0, nq/4) handle Q rows, the rest K rows.
__global__ __launch_bounds__(256) void ln_rope2(
    const short* __restrict__ Xq, short* __restrict__ Yq,
    const short* __restrict__ Xk, short* __restrict__ Yk,
    const float* __restrict__ qg, const float* __restrict__ qbe,
    const float* __restrict__ kg, const float* __restrict__ kbe,
    const float* __restrict__ cosp, const float* __restrict__ sinp,
    int H, int Hkv, int S, int nq)
{
    int gw = blockIdx.x * 4 + (threadIdx.x >> 6);
    const int lane = threadIdx.x & 63;
    const short* X; short* Y; const float* g; const float* bt; int Hc;
    if (gw < nq) { X = Xq; Y = Yq; g = qg; bt = qbe; Hc = H; }
    else { gw -= nq; X = Xk; Y = Yk; g = kg; bt = kbe; Hc = Hkv; }

    const int h  = gw % Hc;
    const int rs = gw / Hc;          // b*S + s
    const int b  = rs / S;
    const int s  = rs - b * S;

    const short* x = X + ((size_t)rs * Hc + h) * 128;
    float x0 = bf2f(x[lane]), x1 = bf2f(x[lane + 64]);

    float sum = x0 + x1;
    float sq  = x0 * x0 + x1 * x1;
#pragma unroll
    for (int off = 32; off > 0; off >>= 1) {
        sum += __shfl_xor(sum, off, 64);
        sq  += __shfl_xor(sq, off, 64);
    }
    float mu  = sum * (1.f / 128.f);
    float var = sq * (1.f / 128.f) - mu * mu;
    float rinv = rsqrtf(var + 1e-5f);

    float y0 = (x0 - mu) * rinv * g[lane]      + bt[lane];
    float y1 = (x1 - mu) * rinv * g[lane + 64] + bt[lane + 64];

    float c0 = cosp[(size_t)s * 128 + lane];
    float c1 = cosp[(size_t)s * 128 + lane + 64];
    float s0 = sinp[(size_t)s * 128 + lane];
    float s1 = sinp[(size_t)s * 128 + lane + 64];

    float o0 = y0 * c0 - y1 * s0;
    float o1 = y1 * c1 + y0 * s1;

    short* yp = Y + ((size_t)(b * Hc + h) * S + s) * 128;
    yp[lane]      = f2bf(o0);
    yp[lane + 64] = f2bf(o1);
}

// Flash attention v3 (proven ~39us): transposed-score formulation +
// block-shared LDS staging, double-buffered.
// Q: bf16 (B,H,S,128). Kt: (B,Hkv,S,128). Vt: (B,Hkv,128,S). O: (B,S,H*128).
__global__ __launch_bounds__(256, 2) void attn(
    const short* __restrict__ Q, const short* __restrict__ Kt,
    const short* __restrict__ Vt, short* __restrict__ O,
    int S, int H, int Hkv, int nrep, float scale)
{
    __shared__ __align__(16) short Ks[2][16 * 512];
    __shared__ __align__(16) short Vs[2][16 * 512];
    __shared__ __align__(16) short P[4][16][72];

    const int w    = threadIdx.x >> 6;
    const int lane = threadIdx.x & 63;
    const int l15  = lane & 15;
    const int quad = lane >> 4;
    const int bh   = blockIdx.x;
    const int h    = bh % H;
    const int b    = bh / H;
    const int nyt  = gridDim.y;
    const int y    = blockIdx.y;
    const int qblk = (y < (nyt >> 1)) ? (nyt - 1 - y) : (y - (nyt >> 1));
    const int hk   = h / nrep;
    const int m0   = qblk * 64 + w * 16;
    const int qpos = m0 + l15;

    const short* qb = Q  + (size_t)(b * H + h) * S * 128;
    const short* kb = Kt + (size_t)(b * Hkv + hk) * S * 128;
    const short* vb = Vt + (size_t)(b * Hkv + hk) * 128 * S;

    auto stage = [&](int buf, int j0) {
#pragma unroll
        for (int i = 0; i < 8; i++) {
            if (w < 2) {
                const int s = w * 8 + i;
                const int t = s >> 2, c = s & 3;
                gl_lds16(kb + (size_t)(j0 + t * 16 + l15) * 128 + c * 32 + quad * 8,
                         Ks[buf] + s * 512 + lane * 8);
            } else {
                const int u = (w - 2) * 8 + i;
                const int c = u >> 1, hf = u & 1;
                gl_lds16(vb + (size_t)(c * 16 + l15) * S + j0 + hf * 32 + quad * 8,
                         Vs[buf] + u * 512 + lane * 8);
            }
        }
    };

    bf16x8 qf[4];
#pragma unroll
    for (int c = 0; c < 4; c++)
        qf[c] = *(const bf16x8*)(qb + (size_t)(m0 + l15) * 128 + c * 32 + quad * 8);

    f32x4 of[8];
#pragma unroll
    for (int c = 0; c < 8; c++) of[c] = f32x4{0.f, 0.f, 0.f, 0.f};
    float m_s = -1e30f, l_s = 0.f;
    const float c2 = scale * 1.44269504f;

    const int nkt = qblk + 1;
    stage(0, 0);
    __syncthreads();

    for (int kt = 0; kt < nkt; kt++) {
        const int cur = kt & 1;
        if (kt + 1 < nkt) stage(cur ^ 1, (kt + 1) * 64);

        const short* Kb = Ks[cur];
        const short* Vb = Vs[cur];
        const int j0 = kt * 64;

        f32x4 sc[4];
#pragma unroll
        for (int t = 0; t < 4; t++) sc[t] = f32x4{0.f, 0.f, 0.f, 0.f};
#pragma unroll
        for (int c = 0; c < 4; c++)
#pragma unroll
            for (int t = 0; t < 4; t++) {
                bf16x8 kf = *(const bf16x8*)(Kb + (t * 4 + c) * 512 + lane * 8);
                sc[t] = MFMA_BF16(kf, qf[c], sc[t], 0, 0, 0);
            }

        float v[4][4];
        float mx = -1e30f;
#pragma unroll
        for (int t = 0; t < 4; t++)
#pragma unroll
            for (int r = 0; r < 4; r++) {
                float s_ = sc[t][r];
                if (j0 + t * 16 + quad * 4 + r > qpos) s_ = -1e30f;
                v[t][r] = s_;
                mx = fmaxf(mx, s_);
            }
        mx = fmaxf(mx, __shfl_xor(mx, 16, 64));
        mx = fmaxf(mx, __shfl_xor(mx, 32, 64));
        float mnew  = fmaxf(m_s, mx);
        float mc    = mnew * c2;
        float alpha = exp2f(m_s * c2 - mc);
        float sum = 0.f;
        float p[4][4];
#pragma unroll
        for (int t = 0; t < 4; t++)
#pragma unroll
            for (int r = 0; r < 4; r++) {
                p[t][r] = exp2f(__builtin_fmaf(v[t][r], c2, -mc));
                sum += p[t][r];
            }
        sum += __shfl_xor(sum, 16, 64);
        sum += __shfl_xor(sum, 32, 64);
        l_s = l_s * alpha + sum;
        m_s = mnew;

#pragma unroll
        for (int c = 0; c < 8; c++) {
            f32x4 t = of[c];
            t[0] *= alpha; t[1] *= alpha; t[2] *= alpha; t[3] *= alpha;
            of[c] = t;
        }

#pragma unroll
        for (int t = 0; t < 4; t++) {
            s16x4 pk;
#pragma unroll
            for (int r = 0; r < 4; r++) pk[r] = f2bf(p[t][r]);
            *(s16x4*)(&P[w][l15][t * 16 + quad * 4]) = pk;
        }
        bf16x8 pb0 = *(const bf16x8*)(&P[w][l15][quad * 8]);
        bf16x8 pb1 = *(const bf16x8*)(&P[w][l15][32 + quad * 8]);

#pragma unroll
        for (int c = 0; c < 8; c++) {
            bf16x8 vf0 = *(const bf16x8*)(Vb + (c * 2 + 0) * 512 + lane * 8);
            bf16x8 vf1 = *(const bf16x8*)(Vb + (c * 2 + 1) * 512 + lane * 8);
            of[c] = MFMA_BF16(vf0, pb0, of[c], 0, 0, 0);
            of[c] = MFMA_BF16(vf1, pb1, of[c], 0, 0, 0);
        }
        __syncthreads();
    }

    const int HDh = H * 128;
    const float rinv = 1.0f / l_s;
    short* orow = O + ((size_t)b * S + qpos) * HDh + h * 128;
#pragma unroll
    for (int c = 0; c < 8; c++) {
        s16x4 ov;
#pragma unroll
        for (int r = 0; r < 4; r++) ov[r] = f2bf(of[c][r] * rinv);
        *(s16x4*)(orow + c * 16 + quad * 4) = ov;
    }
}

extern "C" void kernel_launch(void* const* d_in, const int* in_sizes, int n_in,
                              void* d_out, int out_size, void* d_ws, size_t ws_size,
                              hipStream_t stream) {
    const float* hs   = (const float*)d_in[0];
    const float* cosp = (const float*)d_in[1];
    const float* sinp = (const float*)d_in[2];
    const float* Wq   = (const float*)d_in[3];
    const float* bq   = (const float*)d_in[4];
    const float* Wk   = (const float*)d_in[5];
    const float* bk   = (const float*)d_in[6];
    const float* Wv   = (const float*)d_in[7];
    const float* bv   = (const float*)d_in[8];
    const float* Wo   = (const float*)d_in[9];
    const float* bo   = (const float*)d_in[10];
    const float* qg   = (const float*)d_in[11];
    const float* qb_  = (const float*)d_in[12];
    const float* kg   = (const float*)d_in[13];
    const float* kb_  = (const float*)d_in[14];

    const int Dh    = in_sizes[11];          // 128
    const int Dm    = in_sizes[10];          // 2048
    const int HDh   = in_sizes[4];           // 2048
    const int H     = HDh / Dh;              // 16
    const int HkvDh = in_sizes[6];           // 512
    const int Hkv   = HkvDh / Dh;            // 4
    const int S     = in_sizes[1] / Dh;      // 1024
    const int B     = in_sizes[0] / (S * Dm);// 2
    const int M     = B * S;                 // 2048
    const int nrep  = H / Hkv;               // 4

    // workspace layout; Wqb/Wkb/Wvb contiguous => packed (HDh+2*HkvDh, Dm)
    char* ws = (char*)d_ws;
    short* hsb  = (short*)ws;  ws += (size_t)M * Dm      * 2;  // 8 MB
    short* Wqb  = (short*)ws;  ws += (size_t)HDh * Dm    * 2;  // 8 MB
    short* Wkb  = (short*)ws;  ws += (size_t)HkvDh * Dm  * 2;  // 2 MB
    short* Wvb  = (short*)ws;  ws += (size_t)HkvDh * Dm  * 2;  // 2 MB
    short* Wob  = (short*)ws;  ws += (size_t)Dm * HDh    * 2;  // 8 MB
    short* qg16 = (short*)ws;  ws += (size_t)M * HDh     * 2;  // 8 MB
    short* kg16 = (short*)ws;  ws += (size_t)M * HkvDh   * 2;  // 2 MB
    short* qbuf = (short*)ws;  ws += (size_t)M * HDh     * 2;  // 8 MB
    short* kbuf = (short*)ws;  ws += (size_t)M * HkvDh   * 2;  // 2 MB
    short* vbuf = (short*)ws;  ws += (size_t)M * HkvDh   * 2;  // 2 MB
    short* abuf = qg16;   // alias: q-gemm output dead after ln_rope

    dim3 blk(256);
    const int n0 = M * Dm, n1 = HDh * Dm, n2 = HkvDh * Dm, n3 = HkvDh * Dm, n4 = Dm * HDh;
    cvt5<<<dim3((n0 + n1 + n2 + n3 + n4) / 1024), blk, 0, stream>>>(
        hs, hsb, n0, Wq, Wqb, n1, Wk, Wkb, n2, Wv, Wvb, n3, Wo, Wob, n4);

    const int Ntot = HDh + 2 * HkvDh;  // 3072
    gemm_t<0><<<dim3(Ntot / 64, M / 128), blk, 0, stream>>>(
        hsb, Wqb, bq, bk, bv, qg16, kg16, vbuf, nullptr,
        M, Dm, S, Hkv, HDh, HkvDh, Ntot);

    const int nq = M * H;   // 32768 q row-heads
    ln_rope2<<<dim3((nq + M * Hkv) / 4), blk, 0, stream>>>(
        qg16, qbuf, kg16, kbuf, qg, qb_, kg, kb_, cosp, sinp, H, Hkv, S, nq);

    const float scale = 1.0f / sqrtf((float)Dh);
    attn<<<dim3(H * B, S / 64), blk, 0, stream>>>(qbuf, kbuf, vbuf, abuf, S, H, Hkv, nrep, scale);

    gemm64<<<dim3(Dm / 64, M / 64), blk, 0, stream>>>(
        abuf, Wob, bo, (float*)d_out, HDh, Dm);
}